// Round 9
// baseline (2245.822 us; speedup 1.0000x reference)
//
#include <hip/hip_runtime.h>
#include <hip/hip_bf16.h>

// Problem constants
#define Bz 64
#define Nz 512
#define Ez 1024
#define Hz 16
#define DHz 64

static constexpr int MROWS = Bz * Nz;   // 32768
static constexpr int NQKV  = 3 * Ez;    // 3072

typedef __attribute__((ext_vector_type(8))) short bf16x8_t;   // 8 bf16 = 4 VGPRs
typedef __attribute__((ext_vector_type(4))) float f32x4_t;
typedef __attribute__((ext_vector_type(16))) float f32x16_t;
typedef __attribute__((ext_vector_type(4))) unsigned u32x4_t;

union FragU { bf16x8_t h; u32x4_t u; };

__device__ __forceinline__ unsigned short f2bf(float f) {
    union { float f; unsigned u; } v; v.f = f;
    unsigned r = v.u + 0x7FFFu + ((v.u >> 16) & 1u);   // round-to-nearest-even
    return (unsigned short)(r >> 16);
}
__device__ __forceinline__ float bf2f(unsigned short h) {
    union { unsigned u; float f; } v; v.u = ((unsigned)h) << 16;
    return v.f;
}
// pack two non-negative floats to bf16 pair (lo | hi<<16), round-half-up
__device__ __forceinline__ unsigned packbf(float a, float b) {
    union { float f; unsigned u; } x, y; x.f = a; y.f = b;
    return ((x.u + 0x8000u) >> 16) | ((y.u + 0x8000u) & 0xFFFF0000u);
}

// async global->LDS, 16B per lane. LDS dest = wave-uniform base + lane*16.
__device__ __forceinline__ void async16(const unsigned short* g, unsigned short* l) {
    __builtin_amdgcn_global_load_lds(
        (const __attribute__((address_space(1))) void*)g,
        (__attribute__((address_space(3))) void*)l, 16, 0, 0);
}

// ---------------------------------------------------------------------------
// Convert fp32 -> bf16 (packed, vectorized)
__global__ void cvt_f32_bf16(const float* __restrict__ in,
                             unsigned short* __restrict__ out, int n4) {
    int id = blockIdx.x * blockDim.x + threadIdx.x;
    int stride = gridDim.x * blockDim.x;
    for (int i = id; i < n4; i += stride) {
        float4 f = ((const float4*)in)[i];
        ushort4 o;
        o.x = f2bf(f.x); o.y = f2bf(f.y); o.z = f2bf(f.z); o.w = f2bf(f.w);
        ((ushort4*)out)[i] = o;
    }
}

// Convert + transpose: in [K][Ncols] fp32 -> out [Ncols][K] bf16.
__global__ __launch_bounds__(256)
void cvt_transpose(const float* __restrict__ in,
                   unsigned short* __restrict__ out,
                   int K, int Ncols) {
    int n  = blockIdx.x * 256 + threadIdx.x;
    int k0 = blockIdx.y * 8;
    bf16x8_t o;
#pragma unroll
    for (int j = 0; j < 8; j++)
        o[j] = (short)f2bf(in[(long)(k0 + j) * Ncols + n]);
    *(bf16x8_t*)&out[(long)n * K + k0] = o;
}

// adj[512][512] int -> bitmask adjm[512][8] u64, self-loops baked in
__global__ void build_adjm(const int* __restrict__ adj,
                           unsigned long long* __restrict__ adjm) {
    int id = blockIdx.x * blockDim.x + threadIdx.x;   // 0..4095
    int n = id >> 3, w = id & 7;
    const int4* r4 = (const int4*)(adj + (long)n * Nz + w * 64);
    unsigned long long m = 0;
#pragma unroll
    for (int c = 0; c < 16; c++) {
        int4 v = r4[c];
        unsigned long long bits =
            (unsigned long long)(v.x != 0) | ((unsigned long long)(v.y != 0) << 1) |
            ((unsigned long long)(v.z != 0) << 2) | ((unsigned long long)(v.w != 0) << 3);
        m |= bits << (c * 4);
    }
    if ((n >> 6) == w) m |= 1ull << (n & 63);
    adjm[id] = m;
}

// ---------------------------------------------------------------------------
// bf16 MFMA GEMM v4 (measured best: ~838 TF): C = A @ BT^T + bias.
// 128x128 block tile, BK=64, 256 threads (4 waves), 32x32x16 MFMA,
// global_load_lds width-16 staging, XOR-8 chunk swizzle (p = c ^ (row&7)).
// 32 KiB LDS -> ~3 blocks/CU; implicit wave-level overlap (m114).
template<bool OUT_BF16>
__device__ __forceinline__
void gemm_body(const unsigned short* __restrict__ A,
               const unsigned short* __restrict__ BT,
               const float* __restrict__ bias,
               void* __restrict__ C,
               int M, int Ncols, int K) {
    const int tid  = threadIdx.x;
    const int wave = tid >> 6;
    const int lane = tid & 63;
    const int wm = (wave >> 1) * 64;
    const int wn = (wave & 1) * 64;
    const int m32 = lane & 31;     // row within 32-tile
    const int kh  = lane >> 5;     // k-half selector

    const int rowBase = blockIdx.y * 128;
    const int colBase = blockIdx.x * 128;

    __shared__ __align__(16) unsigned short As[128][64];   // 16 KiB
    __shared__ __align__(16) unsigned short Bs[128][64];   // 16 KiB

    f32x16_t acc[2][2];
#pragma unroll
    for (int i = 0; i < 2; i++)
#pragma unroll
        for (int j = 0; j < 2; j++)
#pragma unroll
            for (int r = 0; r < 16; r++)
                acc[i][j][r] = 0.0f;

    // staging: slot s = tid + cc*256 (s in [0,1024)); row = s>>3, physical
    // chunk p = s&7 holds logical chunk c = p ^ (row&7). Global addresses of
    // 8 consecutive lanes permute within one 128B row segment -> coalesced.
    const unsigned short* pa[4];
    const unsigned short* pb[4];
#pragma unroll
    for (int cc = 0; cc < 4; cc++) {
        int s = tid + cc * 256;
        int r = s >> 3;
        int c = (s & 7) ^ (r & 7);
        pa[cc] = &A [(long)(rowBase + r) * K + c * 8];
        pb[cc] = &BT[(long)(colBase + r) * K + c * 8];
    }
    // fragment-read physical chunk, per kc: p = (kc*2 + kh) ^ (m32&7)
    const int fsw = m32 & 7;

    for (int k0 = 0; k0 < K; k0 += 64) {
        __syncthreads();
#pragma unroll
        for (int cc = 0; cc < 4; cc++) {
            async16(pa[cc] + k0, (unsigned short*)As + (size_t)(cc * 64 + wave * 16) * 32);
            async16(pb[cc] + k0, (unsigned short*)Bs + (size_t)(cc * 64 + wave * 16) * 32);
        }
        __syncthreads();

        bf16x8_t af[2][4], bfr[2][4];
#pragma unroll
        for (int kc = 0; kc < 4; kc++) {
            int p = (kc * 2 + kh) ^ fsw;
#pragma unroll
            for (int t = 0; t < 2; t++) {
                af[t][kc]  = *(bf16x8_t*)&As[wm + t * 32 + m32][p * 8];
                bfr[t][kc] = *(bf16x8_t*)&Bs[wn + t * 32 + m32][p * 8];
            }
        }
#pragma unroll
        for (int kc = 0; kc < 4; kc++)
#pragma unroll
            for (int i = 0; i < 2; i++)
#pragma unroll
                for (int j = 0; j < 2; j++)
                    acc[i][j] = __builtin_amdgcn_mfma_f32_32x32x16_bf16(
                        af[i][kc], bfr[j][kc], acc[i][j], 0, 0, 0);
    }

    // epilogue: C/D layout col=lane&31, row=(reg&3)+8*(reg>>2)+4*kh
#pragma unroll
    for (int j = 0; j < 2; j++) {
        int col = colBase + wn + j * 32 + m32;
        float bv = bias[col];
#pragma unroll
        for (int i = 0; i < 2; i++) {
#pragma unroll
            for (int reg = 0; reg < 16; reg++) {
                int row = rowBase + wm + i * 32 + (reg & 3) + 8 * (reg >> 2) + 4 * kh;
                float v = acc[i][j][reg] + bv;
                if (OUT_BF16)
                    ((unsigned short*)C)[(long)row * Ncols + col] = f2bf(v);
                else
                    ((float*)C)[(long)row * Ncols + col] = v;
            }
        }
    }
}

__global__ __launch_bounds__(256)
void gemm_qkv(const unsigned short* __restrict__ A,
              const unsigned short* __restrict__ BT,
              const float* __restrict__ bias,
              void* __restrict__ C, int M, int Ncols, int K) {
    gemm_body<true>(A, BT, bias, C, M, Ncols, K);
}

__global__ __launch_bounds__(256)
void gemm_proj(const unsigned short* __restrict__ A,
               const unsigned short* __restrict__ BT,
               const float* __restrict__ bias,
               void* __restrict__ C, int M, int Ncols, int K) {
    gemm_body<false>(A, BT, bias, C, M, Ncols, K);
}

// ---------------------------------------------------------------------------
// MFMA flash attention v2: KV-tiled for occupancy.
// Round-8 PMC: 193 us, VALUBusy 53%, MfmaUtil 15%, Occupancy 19% -- the
// 128 KiB LDS forced 1 block/CU (8 waves). Fix: 4 KV-tiles of 128 with
// double-buffered Ks[2][128][64] + Vt[2][64][128] = 64 KiB -> 2 blocks/CU
// (16 waves). T14 staging: issue next tile's global loads BEFORE the 4-ct
// compute phase, ds_write after it, one barrier per KV-tile.
// Math/swizzles identical to the verified v1 (tile-local row/chunk indices).
__global__ __launch_bounds__(512, 4)
void attn_mfma(const unsigned short* __restrict__ qkv,       // [32768][3072] bf16
               const unsigned long long* __restrict__ adjm,  // [512][8]
               unsigned short* __restrict__ y)               // [32768][1024] bf16
{
    const int h = blockIdx.x;
    const int b = blockIdx.y;
    const int tid  = threadIdx.x;
    const int lane = tid & 63;
    const int w    = tid >> 6;
    const int l16  = lane & 15;
    const int q    = lane >> 4;

    __shared__ __align__(16) unsigned short Ks[2][128][64];  // 32 KiB
    __shared__ __align__(16) unsigned short Vt[2][64][128];  // 32 KiB

    const long rowB = (long)b * Nz;
    const unsigned short* base = qkv + rowB * NQKV;

    // staging indices: K covers 128x8 chunk-units per tile, 2 per thread
    const int kn0 = tid >> 3;           // rows 0..63
    const int kn1 = (tid + 512) >> 3;   // rows 64..127
    const int kcc = tid & 7;
    // V: thread handles rows (vnl, vnl+1), d-slice vdh*8..vdh*8+7
    const int vnl = (tid & 63) * 2;
    const int vdh = tid >> 6;

#define KLOAD(kt, n) (*(const bf16x8_t*)&base[(long)((kt) * 128 + (n)) * NQKV + Ez + h * DHz + kcc * 8])
#define VLOAD(kt, n) (*(const bf16x8_t*)&base[(long)((kt) * 128 + (n)) * NQKV + 2 * Ez + h * DHz + vdh * 8])
#define KWRITE(bf, n, v) (*(bf16x8_t*)&Ks[bf][n][(kcc ^ ((n) & 7)) * 8] = (v))

    // Q fragments (registers, hoisted)
    FragU qf[4][2];
#pragma unroll
    for (int mt = 0; mt < 4; mt++)
#pragma unroll
        for (int kc = 0; kc < 2; kc++)
            qf[mt][kc].h = *(const bf16x8_t*)&base[(long)(w * 64 + mt * 16 + l16) * NQKV
                                                   + h * DHz + kc * 32 + q * 8];

    // prologue: stage tile 0 into buf 0
    {
        bf16x8_t ka = KLOAD(0, kn0), kb = KLOAD(0, kn1);
        bf16x8_t va = VLOAD(0, vnl), vb = VLOAD(0, vnl + 1);
        KWRITE(0, kn0, ka); KWRITE(0, kn1, kb);
#pragma unroll
        for (int dd = 0; dd < 8; dd++) {
            int d = vdh * 8 + dd;
            unsigned lo = (unsigned)(unsigned short)va[dd];
            unsigned hi = (unsigned)(unsigned short)vb[dd];
            int cp = (vnl >> 3) ^ (d & 7);
            *(unsigned*)&Vt[0][d][cp * 8 + (vnl & 7)] = lo | (hi << 16);
        }
    }
    __syncthreads();

    f32x4_t oacc[4][4];
#pragma unroll
    for (int mt = 0; mt < 4; mt++)
#pragma unroll
        for (int dt = 0; dt < 4; dt++) {
            f32x4_t z = {0.0f, 0.0f, 0.0f, 0.0f};
            oacc[mt][dt] = z;
        }
    float rsum[4] = {0.0f, 0.0f, 0.0f, 0.0f};
    unsigned long long wm[4];

    for (int kt = 0; kt < 4; kt++) {
        const int buf = kt & 1;

        // T14: issue next tile's global loads before compute
        bf16x8_t ka, kb, va, vb;
        if (kt < 3) {
            ka = KLOAD(kt + 1, kn0); kb = KLOAD(kt + 1, kn1);
            va = VLOAD(kt + 1, vnl); vb = VLOAD(kt + 1, vnl + 1);
        }

#pragma unroll
        for (int lt = 0; lt < 4; lt++) {
            const int ct = kt * 4 + lt;
            if ((ct & 1) == 0) {
#pragma unroll
                for (int mt = 0; mt < 4; mt++)
                    wm[mt] = adjm[(size_t)(w * 64 + mt * 16 + l16) * 8 + (ct >> 1)];
            }
            bf16x8_t kf[2][2];
#pragma unroll
            for (int jt = 0; jt < 2; jt++)
#pragma unroll
                for (int kc = 0; kc < 2; kc++)
                    kf[jt][kc] = *(const bf16x8_t*)
                        &Ks[buf][lt * 32 + jt * 16 + l16][((kc * 4 + q) ^ (l16 & 7)) * 8];

            f32x4_t tacc[2][4];
            __builtin_amdgcn_s_setprio(1);
#pragma unroll
            for (int jt = 0; jt < 2; jt++)
#pragma unroll
                for (int mt = 0; mt < 4; mt++) {
                    f32x4_t z = {0.0f, 0.0f, 0.0f, 0.0f};
                    z = __builtin_amdgcn_mfma_f32_16x16x32_bf16(kf[jt][0], qf[mt][0].h, z, 0, 0, 0);
                    tacc[jt][mt] = __builtin_amdgcn_mfma_f32_16x16x32_bf16(kf[jt][1], qf[mt][1].h, z, 0, 0, 0);
                }
            __builtin_amdgcn_s_setprio(0);

            unsigned pk[2][4][2];
#pragma unroll
            for (int jt = 0; jt < 2; jt++)
#pragma unroll
                for (int mt = 0; mt < 4; mt++) {
                    float e[4];
#pragma unroll
                    for (int r = 0; r < 4; r++) {
                        int jrel = (ct & 1) * 32 + jt * 16 + q * 4 + r;
                        bool bit = (wm[mt] >> jrel) & 1ull;
                        float ev = bit ? __expf(tacc[jt][mt][r] * 0.125f) : 0.0f;
                        e[r] = ev;
                        rsum[mt] += ev;
                    }
                    pk[jt][mt][0] = packbf(e[0], e[1]);
                    pk[jt][mt][1] = packbf(e[2], e[3]);
                }

            bf16x8_t vf[4];
#pragma unroll
            for (int dt = 0; dt < 4; dt++) {
                int d = dt * 16 + l16;
                int cp = (lt * 4 + q) ^ (l16 & 7);
                vf[dt] = *(const bf16x8_t*)&Vt[buf][d][cp * 8];
            }

#pragma unroll
            for (int mt = 0; mt < 4; mt++) {
                FragU pf;
#pragma unroll
                for (int p = 0; p < 4; p++) {
                    int srcl = ((lane & 16) << 1) | ((p & 2) << 3) | l16;
                    unsigned a0 = (unsigned)__shfl((int)pk[0][mt][p & 1], srcl);
                    unsigned a1 = (unsigned)__shfl((int)pk[1][mt][p & 1], srcl);
                    pf.u[p] = (lane & 32) ? a1 : a0;
                }
                __builtin_amdgcn_s_setprio(1);
#pragma unroll
                for (int dt = 0; dt < 4; dt++)
                    oacc[mt][dt] = __builtin_amdgcn_mfma_f32_16x16x32_bf16(
                        pf.h, vf[dt], oacc[mt][dt], 0, 0, 0);
                __builtin_amdgcn_s_setprio(0);
            }
        }

        // write next tile into the other buffer; one barrier per KV-tile
        if (kt < 3) {
            KWRITE(buf ^ 1, kn0, ka); KWRITE(buf ^ 1, kn1, kb);
#pragma unroll
            for (int dd = 0; dd < 8; dd++) {
                int d = vdh * 8 + dd;
                unsigned lo = (unsigned)(unsigned short)va[dd];
                unsigned hi = (unsigned)(unsigned short)vb[dd];
                int cp = (vnl >> 3) ^ (d & 7);
                *(unsigned*)&Vt[buf ^ 1][d][cp * 8 + (vnl & 7)] = lo | (hi << 16);
            }
            __syncthreads();
        }
    }
#undef KLOAD
#undef VLOAD
#undef KWRITE

#pragma unroll
    for (int mt = 0; mt < 4; mt++) {
        float s = rsum[mt];
        s += __shfl_xor(s, 16);
        s += __shfl_xor(s, 32);
#pragma unroll
        for (int r = 0; r < 4; r++) {
            float rs = __shfl(s, (lane & 48) | (q * 4) | r);
            float inv = 1.0f / rs;
            int row = w * 64 + mt * 16 + q * 4 + r;
#pragma unroll
            for (int dt = 0; dt < 4; dt++)
                y[(rowB + row) * Ez + h * DHz + dt * 16 + l16] =
                    f2bf(oacc[mt][dt][r] * inv);
        }
    }
}

// ---------------------------------------------------------------------------
extern "C" void kernel_launch(void* const* d_in, const int* in_sizes, int n_in,
                              void* d_out, int out_size, void* d_ws, size_t ws_size,
                              hipStream_t stream) {
    const float* x     = (const float*)d_in[0];
    const float* Wqkv  = (const float*)d_in[1];
    const float* bqkv  = (const float*)d_in[2];
    const float* Wproj = (const float*)d_in[3];
    const float* bproj = (const float*)d_in[4];
    const int*   adj   = (const int*)d_in[5];
    float* out = (float*)d_out;

    char* ws = (char*)d_ws;
    unsigned short* xb     = (unsigned short*)(ws);                 // 67 MB (also yb)
    unsigned short* qkv    = (unsigned short*)(ws + 67108864);      // 201 MB
    unsigned short* WqkvT  = (unsigned short*)(ws + 268435456);     // 6 MB
    unsigned short* WprojT = (unsigned short*)(ws + 274726912);     // 2 MB
    unsigned long long* adjm = (unsigned long long*)(ws + 276824064); // 32 KB
    unsigned short* yb = xb;  // reuse: xb consumed by gemm1 before attn writes yb

    // 1. casts / transposes / adjacency bitmask
    cvt_f32_bf16<<<8192, 256, 0, stream>>>(x, xb, (Bz * Nz * Ez) / 4);
    cvt_transpose<<<dim3(NQKV / 256, Ez / 8), 256, 0, stream>>>(Wqkv, WqkvT, Ez, NQKV);
    cvt_transpose<<<dim3(Ez / 256, Ez / 8), 256, 0, stream>>>(Wproj, WprojT, Ez, Ez);
    build_adjm<<<16, 256, 0, stream>>>(adj, adjm);

    // 2. QKV projection (fused single launch — the 3-way split cost ~75 us:
    //    A re-fetched thrice + extra launches)
    gemm_qkv<<<dim3(NQKV / 128, MROWS / 128), 256, 0, stream>>>(
        xb, WqkvT, bqkv, qkv, MROWS, NQKV, Ez);

    // 3. MFMA flash attention (KV-tiled, 64 KiB LDS -> 2 blocks/CU)
    attn_mfma<<<dim3(Hz, Bz), 512, 0, stream>>>(qkv, adjm, yb);

    // 4. output projection: out = yb @ Wproj + bproj (fp32 out)
    gemm_proj<<<dim3(Ez / 128, MROWS / 128), 256, 0, stream>>>(
        yb, WprojT, bproj, out, MROWS, Ez, Ez);
}

// Round 11
// 792.609 us; speedup vs baseline: 2.8335x; 2.8335x over previous
//
#include <hip/hip_runtime.h>
#include <hip/hip_bf16.h>

// Problem constants
#define Bz 64
#define Nz 512
#define Ez 1024
#define Hz 16
#define DHz 64

static constexpr int MROWS = Bz * Nz;   // 32768
static constexpr int NQKV  = 3 * Ez;    // 3072

typedef __attribute__((ext_vector_type(8))) short bf16x8_t;   // 8 bf16 = 4 VGPRs
typedef __attribute__((ext_vector_type(4))) float f32x4_t;
typedef __attribute__((ext_vector_type(16))) float f32x16_t;
typedef __attribute__((ext_vector_type(4))) unsigned u32x4_t;

union FragU { bf16x8_t h; u32x4_t u; };

__device__ __forceinline__ unsigned short f2bf(float f) {
    union { float f; unsigned u; } v; v.f = f;
    unsigned r = v.u + 0x7FFFu + ((v.u >> 16) & 1u);   // round-to-nearest-even
    return (unsigned short)(r >> 16);
}
__device__ __forceinline__ float bf2f(unsigned short h) {
    union { unsigned u; float f; } v; v.u = ((unsigned)h) << 16;
    return v.f;
}
// pack two non-negative floats to bf16 pair (lo | hi<<16), round-half-up
__device__ __forceinline__ unsigned packbf(float a, float b) {
    union { float f; unsigned u; } x, y; x.f = a; y.f = b;
    return ((x.u + 0x8000u) >> 16) | ((y.u + 0x8000u) & 0xFFFF0000u);
}

// async global->LDS, 16B per lane. LDS dest = wave-uniform base + lane*16.
__device__ __forceinline__ void async16(const unsigned short* g, unsigned short* l) {
    __builtin_amdgcn_global_load_lds(
        (const __attribute__((address_space(1))) void*)g,
        (__attribute__((address_space(3))) void*)l, 16, 0, 0);
}

// ---------------------------------------------------------------------------
// Convert fp32 -> bf16 (packed, vectorized)
__global__ void cvt_f32_bf16(const float* __restrict__ in,
                             unsigned short* __restrict__ out, int n4) {
    int id = blockIdx.x * blockDim.x + threadIdx.x;
    int stride = gridDim.x * blockDim.x;
    for (int i = id; i < n4; i += stride) {
        float4 f = ((const float4*)in)[i];
        ushort4 o;
        o.x = f2bf(f.x); o.y = f2bf(f.y); o.z = f2bf(f.z); o.w = f2bf(f.w);
        ((ushort4*)out)[i] = o;
    }
}

// Convert + transpose: in [K][Ncols] fp32 -> out [Ncols][K] bf16.
__global__ __launch_bounds__(256)
void cvt_transpose(const float* __restrict__ in,
                   unsigned short* __restrict__ out,
                   int K, int Ncols) {
    int n  = blockIdx.x * 256 + threadIdx.x;
    int k0 = blockIdx.y * 8;
    bf16x8_t o;
#pragma unroll
    for (int j = 0; j < 8; j++)
        o[j] = (short)f2bf(in[(long)(k0 + j) * Ncols + n]);
    *(bf16x8_t*)&out[(long)n * K + k0] = o;
}

// adj[512][512] int -> bitmask adjm[512][8] u64, self-loops baked in
__global__ void build_adjm(const int* __restrict__ adj,
                           unsigned long long* __restrict__ adjm) {
    int id = blockIdx.x * blockDim.x + threadIdx.x;   // 0..4095
    int n = id >> 3, w = id & 7;
    const int4* r4 = (const int4*)(adj + (long)n * Nz + w * 64);
    unsigned long long m = 0;
#pragma unroll
    for (int c = 0; c < 16; c++) {
        int4 v = r4[c];
        unsigned long long bits =
            (unsigned long long)(v.x != 0) | ((unsigned long long)(v.y != 0) << 1) |
            ((unsigned long long)(v.z != 0) << 2) | ((unsigned long long)(v.w != 0) << 3);
        m |= bits << (c * 4);
    }
    if ((n >> 6) == w) m |= 1ull << (n & 63);
    adjm[id] = m;
}

// ---------------------------------------------------------------------------
// bf16 MFMA GEMM v4 (measured best: ~838 TF): C = A @ BT^T + bias.
// 128x128 block tile, BK=64, 256 threads (4 waves), 32x32x16 MFMA,
// global_load_lds width-16 staging, XOR-8 chunk swizzle (p = c ^ (row&7)).
// 32 KiB LDS -> ~3 blocks/CU; implicit wave-level overlap (m114).
template<bool OUT_BF16>
__device__ __forceinline__
void gemm_body(const unsigned short* __restrict__ A,
               const unsigned short* __restrict__ BT,
               const float* __restrict__ bias,
               void* __restrict__ C,
               int M, int Ncols, int K) {
    const int tid  = threadIdx.x;
    const int wave = tid >> 6;
    const int lane = tid & 63;
    const int wm = (wave >> 1) * 64;
    const int wn = (wave & 1) * 64;
    const int m32 = lane & 31;     // row within 32-tile
    const int kh  = lane >> 5;     // k-half selector

    const int rowBase = blockIdx.y * 128;
    const int colBase = blockIdx.x * 128;

    __shared__ __align__(16) unsigned short As[128][64];   // 16 KiB
    __shared__ __align__(16) unsigned short Bs[128][64];   // 16 KiB

    f32x16_t acc[2][2];
#pragma unroll
    for (int i = 0; i < 2; i++)
#pragma unroll
        for (int j = 0; j < 2; j++)
#pragma unroll
            for (int r = 0; r < 16; r++)
                acc[i][j][r] = 0.0f;

    // staging: slot s = tid + cc*256 (s in [0,1024)); row = s>>3, physical
    // chunk p = s&7 holds logical chunk c = p ^ (row&7). Global addresses of
    // 8 consecutive lanes permute within one 128B row segment -> coalesced.
    const unsigned short* pa[4];
    const unsigned short* pb[4];
#pragma unroll
    for (int cc = 0; cc < 4; cc++) {
        int s = tid + cc * 256;
        int r = s >> 3;
        int c = (s & 7) ^ (r & 7);
        pa[cc] = &A [(long)(rowBase + r) * K + c * 8];
        pb[cc] = &BT[(long)(colBase + r) * K + c * 8];
    }
    // fragment-read physical chunk, per kc: p = (kc*2 + kh) ^ (m32&7)
    const int fsw = m32 & 7;

    for (int k0 = 0; k0 < K; k0 += 64) {
        __syncthreads();
#pragma unroll
        for (int cc = 0; cc < 4; cc++) {
            async16(pa[cc] + k0, (unsigned short*)As + (size_t)(cc * 64 + wave * 16) * 32);
            async16(pb[cc] + k0, (unsigned short*)Bs + (size_t)(cc * 64 + wave * 16) * 32);
        }
        __syncthreads();

        bf16x8_t af[2][4], bfr[2][4];
#pragma unroll
        for (int kc = 0; kc < 4; kc++) {
            int p = (kc * 2 + kh) ^ fsw;
#pragma unroll
            for (int t = 0; t < 2; t++) {
                af[t][kc]  = *(bf16x8_t*)&As[wm + t * 32 + m32][p * 8];
                bfr[t][kc] = *(bf16x8_t*)&Bs[wn + t * 32 + m32][p * 8];
            }
        }
#pragma unroll
        for (int kc = 0; kc < 4; kc++)
#pragma unroll
            for (int i = 0; i < 2; i++)
#pragma unroll
                for (int j = 0; j < 2; j++)
                    acc[i][j] = __builtin_amdgcn_mfma_f32_32x32x16_bf16(
                        af[i][kc], bfr[j][kc], acc[i][j], 0, 0, 0);
    }

    // epilogue: C/D layout col=lane&31, row=(reg&3)+8*(reg>>2)+4*kh
#pragma unroll
    for (int j = 0; j < 2; j++) {
        int col = colBase + wn + j * 32 + m32;
        float bv = bias[col];
#pragma unroll
        for (int i = 0; i < 2; i++) {
#pragma unroll
            for (int reg = 0; reg < 16; reg++) {
                int row = rowBase + wm + i * 32 + (reg & 3) + 8 * (reg >> 2) + 4 * kh;
                float v = acc[i][j][reg] + bv;
                if (OUT_BF16)
                    ((unsigned short*)C)[(long)row * Ncols + col] = f2bf(v);
                else
                    ((float*)C)[(long)row * Ncols + col] = v;
            }
        }
    }
}

__global__ __launch_bounds__(256)
void gemm_qkv(const unsigned short* __restrict__ A,
              const unsigned short* __restrict__ BT,
              const float* __restrict__ bias,
              void* __restrict__ C, int M, int Ncols, int K) {
    gemm_body<true>(A, BT, bias, C, M, Ncols, K);
}

__global__ __launch_bounds__(256)
void gemm_proj(const unsigned short* __restrict__ A,
               const unsigned short* __restrict__ BT,
               const float* __restrict__ bias,
               void* __restrict__ C, int M, int Ncols, int K) {
    gemm_body<false>(A, BT, bias, C, M, Ncols, K);
}

// ---------------------------------------------------------------------------
// MFMA flash attention v3: v1 structure, halved LDS for occupancy.
// Round-8 PMC (v1): 193 us, VALUBusy 53%, MfmaUtil 15%, Occ 19% — 128 KiB
// LDS forced 1 block/CU. Round-9 (v2, reg-prefetch dbuf): VGPR starved to
// 64 -> 5.6 GB spill traffic, 1700 us. v3: NO prefetch registers — exactly
// v1's stage->barrier->compute shape, but K/V split into two sequential
// 256-row tiles: Ks[256][64] + Vt[64][256] = 64 KiB -> 2 blocks/CU
// (16 waves); the other block's waves cover the serial staging (m114).
// Swizzles re-derived for half tile: V write cp=(n0>>3)^(d&7), n0 in
// [0,256) <-> read cp=(lt*4+q)^(l16&7), lt=ct&7 in [0,8); K XOR key n&7
// unchanged. Register footprint = v1 (~92 VGPR), launch_bounds (512,2).
__global__ __launch_bounds__(512, 2)
void attn_mfma(const unsigned short* __restrict__ qkv,       // [32768][3072] bf16
               const unsigned long long* __restrict__ adjm,  // [512][8]
               unsigned short* __restrict__ y)               // [32768][1024] bf16
{
    const int h = blockIdx.x;
    const int b = blockIdx.y;
    const int tid  = threadIdx.x;
    const int lane = tid & 63;
    const int w    = tid >> 6;
    const int l16  = lane & 15;
    const int q    = lane >> 4;

    __shared__ __align__(16) unsigned short Ks[256][64];   // 32 KiB
    __shared__ __align__(16) unsigned short Vt[64][256];   // 32 KiB (V^T)

    const long rowB = (long)b * Nz;
    const unsigned short* base = qkv + rowB * NQKV;

    // Q fragments (registers, hoisted — no LDS dependency)
    FragU qf[4][2];
#pragma unroll
    for (int mt = 0; mt < 4; mt++)
#pragma unroll
        for (int kc = 0; kc < 2; kc++)
            qf[mt][kc].h = *(const bf16x8_t*)&base[(long)(w * 64 + mt * 16 + l16) * NQKV
                                                   + h * DHz + kc * 32 + q * 8];

    f32x4_t oacc[4][4];
#pragma unroll
    for (int mt = 0; mt < 4; mt++)
#pragma unroll
        for (int dt = 0; dt < 4; dt++) {
            f32x4_t z = {0.0f, 0.0f, 0.0f, 0.0f};
            oacc[mt][dt] = z;
        }
    float rsum[4] = {0.0f, 0.0f, 0.0f, 0.0f};
    unsigned long long wm[4];

    for (int kt = 0; kt < 2; kt++) {
        // barrier before overwriting the tile (all reads of previous done)
        if (kt) __syncthreads();

        // ---- stage K tile: 256 rows x 8 chunks, XOR-swizzled ----
        for (int idx = tid; idx < 2048; idx += 512) {
            int n = idx >> 3, cc = idx & 7;
            *(bf16x8_t*)&Ks[n][(cc ^ (n & 7)) * 8] =
                *(const bf16x8_t*)&base[(long)(kt * 256 + n) * NQKV + Ez + h * DHz + cc * 8];
        }
        // ---- stage V^T tile: thread handles rows (n0,n0+1) x 16 d's ----
        {
            int tp = tid & 127, dh = tid >> 7;   // dh in [0,4)
            int n0 = tp * 2;
            bf16x8_t va[2], vb[2];
#pragma unroll
            for (int c = 0; c < 2; c++) {
                va[c] = *(const bf16x8_t*)&base[(long)(kt * 256 + n0) * NQKV + 2 * Ez + h * DHz + dh * 16 + c * 8];
                vb[c] = *(const bf16x8_t*)&base[(long)(kt * 256 + n0 + 1) * NQKV + 2 * Ez + h * DHz + dh * 16 + c * 8];
            }
#pragma unroll
            for (int dd = 0; dd < 16; dd++) {
                int d = dh * 16 + dd;
                unsigned lo = (unsigned)(unsigned short)va[dd >> 3][dd & 7];
                unsigned hi = (unsigned)(unsigned short)vb[dd >> 3][dd & 7];
                int cp = (n0 >> 3) ^ (d & 7);
                *(unsigned*)&Vt[d][cp * 8 + (n0 & 7)] = lo | (hi << 16);
            }
        }
        __syncthreads();

        // ---- 8 column-tiles of 32 within this KV tile ----
#pragma unroll
        for (int lt = 0; lt < 8; lt++) {
            const int ct = kt * 8 + lt;
            if ((ct & 1) == 0) {
#pragma unroll
                for (int mt = 0; mt < 4; mt++)
                    wm[mt] = adjm[(size_t)(w * 64 + mt * 16 + l16) * 8 + (ct >> 1)];
            }
            bf16x8_t kf[2][2];
#pragma unroll
            for (int jt = 0; jt < 2; jt++)
#pragma unroll
                for (int kc = 0; kc < 2; kc++)
                    kf[jt][kc] = *(const bf16x8_t*)
                        &Ks[lt * 32 + jt * 16 + l16][((kc * 4 + q) ^ (l16 & 7)) * 8];

            f32x4_t tacc[2][4];
            __builtin_amdgcn_s_setprio(1);
#pragma unroll
            for (int jt = 0; jt < 2; jt++)
#pragma unroll
                for (int mt = 0; mt < 4; mt++) {
                    f32x4_t z = {0.0f, 0.0f, 0.0f, 0.0f};
                    z = __builtin_amdgcn_mfma_f32_16x16x32_bf16(kf[jt][0], qf[mt][0].h, z, 0, 0, 0);
                    tacc[jt][mt] = __builtin_amdgcn_mfma_f32_16x16x32_bf16(kf[jt][1], qf[mt][1].h, z, 0, 0, 0);
                }
            __builtin_amdgcn_s_setprio(0);

            unsigned pk[2][4][2];
#pragma unroll
            for (int jt = 0; jt < 2; jt++)
#pragma unroll
                for (int mt = 0; mt < 4; mt++) {
                    float e[4];
#pragma unroll
                    for (int r = 0; r < 4; r++) {
                        int jrel = (ct & 1) * 32 + jt * 16 + q * 4 + r;
                        bool bit = (wm[mt] >> jrel) & 1ull;
                        float ev = bit ? __expf(tacc[jt][mt][r] * 0.125f) : 0.0f;
                        e[r] = ev;
                        rsum[mt] += ev;
                    }
                    pk[jt][mt][0] = packbf(e[0], e[1]);
                    pk[jt][mt][1] = packbf(e[2], e[3]);
                }

            bf16x8_t vf[4];
#pragma unroll
            for (int dt = 0; dt < 4; dt++) {
                int d = dt * 16 + l16;
                int cp = (lt * 4 + q) ^ (l16 & 7);
                vf[dt] = *(const bf16x8_t*)&Vt[d][cp * 8];
            }

#pragma unroll
            for (int mt = 0; mt < 4; mt++) {
                FragU pf;
#pragma unroll
                for (int p = 0; p < 4; p++) {
                    int srcl = ((lane & 16) << 1) | ((p & 2) << 3) | l16;
                    unsigned a0 = (unsigned)__shfl((int)pk[0][mt][p & 1], srcl);
                    unsigned a1 = (unsigned)__shfl((int)pk[1][mt][p & 1], srcl);
                    pf.u[p] = (lane & 32) ? a1 : a0;
                }
                __builtin_amdgcn_s_setprio(1);
#pragma unroll
                for (int dt = 0; dt < 4; dt++)
                    oacc[mt][dt] = __builtin_amdgcn_mfma_f32_16x16x32_bf16(
                        pf.h, vf[dt], oacc[mt][dt], 0, 0, 0);
                __builtin_amdgcn_s_setprio(0);
            }
        }
    }

#pragma unroll
    for (int mt = 0; mt < 4; mt++) {
        float s = rsum[mt];
        s += __shfl_xor(s, 16);
        s += __shfl_xor(s, 32);
#pragma unroll
        for (int r = 0; r < 4; r++) {
            float rs = __shfl(s, (lane & 48) | (q * 4) | r);
            float inv = 1.0f / rs;
            int row = w * 64 + mt * 16 + q * 4 + r;
#pragma unroll
            for (int dt = 0; dt < 4; dt++)
                y[(rowB + row) * Ez + h * DHz + dt * 16 + l16] =
                    f2bf(oacc[mt][dt][r] * inv);
        }
    }
}

// ---------------------------------------------------------------------------
extern "C" void kernel_launch(void* const* d_in, const int* in_sizes, int n_in,
                              void* d_out, int out_size, void* d_ws, size_t ws_size,
                              hipStream_t stream) {
    const float* x     = (const float*)d_in[0];
    const float* Wqkv  = (const float*)d_in[1];
    const float* bqkv  = (const float*)d_in[2];
    const float* Wproj = (const float*)d_in[3];
    const float* bproj = (const float*)d_in[4];
    const int*   adj   = (const int*)d_in[5];
    float* out = (float*)d_out;

    char* ws = (char*)d_ws;
    unsigned short* xb     = (unsigned short*)(ws);                 // 67 MB (also yb)
    unsigned short* qkv    = (unsigned short*)(ws + 67108864);      // 201 MB
    unsigned short* WqkvT  = (unsigned short*)(ws + 268435456);     // 6 MB
    unsigned short* WprojT = (unsigned short*)(ws + 274726912);     // 2 MB
    unsigned long long* adjm = (unsigned long long*)(ws + 276824064); // 32 KB
    unsigned short* yb = xb;  // reuse: xb consumed by gemm1 before attn writes yb

    // 1. casts / transposes / adjacency bitmask
    cvt_f32_bf16<<<8192, 256, 0, stream>>>(x, xb, (Bz * Nz * Ez) / 4);
    cvt_transpose<<<dim3(NQKV / 256, Ez / 8), 256, 0, stream>>>(Wqkv, WqkvT, Ez, NQKV);
    cvt_transpose<<<dim3(Ez / 256, Ez / 8), 256, 0, stream>>>(Wproj, WprojT, Ez, Ez);
    build_adjm<<<16, 256, 0, stream>>>(adj, adjm);

    // 2. QKV projection (fused single launch)
    gemm_qkv<<<dim3(NQKV / 128, MROWS / 128), 256, 0, stream>>>(
        xb, WqkvT, bqkv, qkv, MROWS, NQKV, Ez);

    // 3. MFMA flash attention (2x256 KV tiles, 64 KiB LDS -> 2 blocks/CU)
    attn_mfma<<<dim3(Hz, Bz), 512, 0, stream>>>(qkv, adjm, yb);

    // 4. output projection: out = yb @ Wproj + bproj (fp32 out)
    gemm_proj<<<dim3(Ez / 128, MROWS / 128), 256, 0, stream>>>(
        yb, WprojT, bproj, out, MROWS, Ez, Ez);
}

// Round 12
// 767.155 us; speedup vs baseline: 2.9275x; 1.0332x over previous
//
#include <hip/hip_runtime.h>
#include <hip/hip_bf16.h>

// Problem constants
#define Bz 64
#define Nz 512
#define Ez 1024
#define Hz 16
#define DHz 64

static constexpr int MROWS = Bz * Nz;   // 32768
static constexpr int NQKV  = 3 * Ez;    // 3072

typedef __attribute__((ext_vector_type(8))) short bf16x8_t;   // 8 bf16 = 4 VGPRs
typedef __attribute__((ext_vector_type(4))) float f32x4_t;
typedef __attribute__((ext_vector_type(16))) float f32x16_t;
typedef __attribute__((ext_vector_type(4))) unsigned u32x4_t;

union FragU { bf16x8_t h; u32x4_t u; };

__device__ __forceinline__ unsigned short f2bf(float f) {
    union { float f; unsigned u; } v; v.f = f;
    unsigned r = v.u + 0x7FFFu + ((v.u >> 16) & 1u);   // round-to-nearest-even
    return (unsigned short)(r >> 16);
}
__device__ __forceinline__ float bf2f(unsigned short h) {
    union { unsigned u; float f; } v; v.u = ((unsigned)h) << 16;
    return v.f;
}
// pack two non-negative floats to bf16 pair (lo | hi<<16), round-half-up
__device__ __forceinline__ unsigned packbf(float a, float b) {
    union { float f; unsigned u; } x, y; x.f = a; y.f = b;
    return ((x.u + 0x8000u) >> 16) | ((y.u + 0x8000u) & 0xFFFF0000u);
}

// async global->LDS, 16B per lane. LDS dest = wave-uniform base + lane*16.
__device__ __forceinline__ void async16(const unsigned short* g, unsigned short* l) {
    __builtin_amdgcn_global_load_lds(
        (const __attribute__((address_space(1))) void*)g,
        (__attribute__((address_space(3))) void*)l, 16, 0, 0);
}

// ---------------------------------------------------------------------------
// Convert fp32 -> bf16 (packed, vectorized)
__global__ void cvt_f32_bf16(const float* __restrict__ in,
                             unsigned short* __restrict__ out, int n4) {
    int id = blockIdx.x * blockDim.x + threadIdx.x;
    int stride = gridDim.x * blockDim.x;
    for (int i = id; i < n4; i += stride) {
        float4 f = ((const float4*)in)[i];
        ushort4 o;
        o.x = f2bf(f.x); o.y = f2bf(f.y); o.z = f2bf(f.z); o.w = f2bf(f.w);
        ((ushort4*)out)[i] = o;
    }
}

// Convert + transpose: in [K][Ncols] fp32 -> out [Ncols][K] bf16.
__global__ __launch_bounds__(256)
void cvt_transpose(const float* __restrict__ in,
                   unsigned short* __restrict__ out,
                   int K, int Ncols) {
    int n  = blockIdx.x * 256 + threadIdx.x;
    int k0 = blockIdx.y * 8;
    bf16x8_t o;
#pragma unroll
    for (int j = 0; j < 8; j++)
        o[j] = (short)f2bf(in[(long)(k0 + j) * Ncols + n]);
    *(bf16x8_t*)&out[(long)n * K + k0] = o;
}

// adj[512][512] int -> bitmask adjm[512][8] u64, self-loops baked in
__global__ void build_adjm(const int* __restrict__ adj,
                           unsigned long long* __restrict__ adjm) {
    int id = blockIdx.x * blockDim.x + threadIdx.x;   // 0..4095
    int n = id >> 3, w = id & 7;
    const int4* r4 = (const int4*)(adj + (long)n * Nz + w * 64);
    unsigned long long m = 0;
#pragma unroll
    for (int c = 0; c < 16; c++) {
        int4 v = r4[c];
        unsigned long long bits =
            (unsigned long long)(v.x != 0) | ((unsigned long long)(v.y != 0) << 1) |
            ((unsigned long long)(v.z != 0) << 2) | ((unsigned long long)(v.w != 0) << 3);
        m |= bits << (c * 4);
    }
    if ((n >> 6) == w) m |= 1ull << (n & 63);
    adjm[id] = m;
}

// ---------------------------------------------------------------------------
// bf16 MFMA GEMM v4 (measured best: ~838 TF): C = A @ BT^T + bias.
// 128x128 block tile, BK=64, 256 threads (4 waves), 32x32x16 MFMA,
// global_load_lds width-16 staging, XOR-8 chunk swizzle (p = c ^ (row&7)).
// 32 KiB LDS -> ~3 blocks/CU; implicit wave-level overlap (m114).
template<bool OUT_BF16>
__device__ __forceinline__
void gemm_body(const unsigned short* __restrict__ A,
               const unsigned short* __restrict__ BT,
               const float* __restrict__ bias,
               void* __restrict__ C,
               int M, int Ncols, int K) {
    const int tid  = threadIdx.x;
    const int wave = tid >> 6;
    const int lane = tid & 63;
    const int wm = (wave >> 1) * 64;
    const int wn = (wave & 1) * 64;
    const int m32 = lane & 31;     // row within 32-tile
    const int kh  = lane >> 5;     // k-half selector

    const int rowBase = blockIdx.y * 128;
    const int colBase = blockIdx.x * 128;

    __shared__ __align__(16) unsigned short As[128][64];   // 16 KiB
    __shared__ __align__(16) unsigned short Bs[128][64];   // 16 KiB

    f32x16_t acc[2][2];
#pragma unroll
    for (int i = 0; i < 2; i++)
#pragma unroll
        for (int j = 0; j < 2; j++)
#pragma unroll
            for (int r = 0; r < 16; r++)
                acc[i][j][r] = 0.0f;

    // staging: slot s = tid + cc*256 (s in [0,1024)); row = s>>3, physical
    // chunk p = s&7 holds logical chunk c = p ^ (row&7). Global addresses of
    // 8 consecutive lanes permute within one 128B row segment -> coalesced.
    const unsigned short* pa[4];
    const unsigned short* pb[4];
#pragma unroll
    for (int cc = 0; cc < 4; cc++) {
        int s = tid + cc * 256;
        int r = s >> 3;
        int c = (s & 7) ^ (r & 7);
        pa[cc] = &A [(long)(rowBase + r) * K + c * 8];
        pb[cc] = &BT[(long)(colBase + r) * K + c * 8];
    }
    // fragment-read physical chunk, per kc: p = (kc*2 + kh) ^ (m32&7)
    const int fsw = m32 & 7;

    for (int k0 = 0; k0 < K; k0 += 64) {
        __syncthreads();
#pragma unroll
        for (int cc = 0; cc < 4; cc++) {
            async16(pa[cc] + k0, (unsigned short*)As + (size_t)(cc * 64 + wave * 16) * 32);
            async16(pb[cc] + k0, (unsigned short*)Bs + (size_t)(cc * 64 + wave * 16) * 32);
        }
        __syncthreads();

        bf16x8_t af[2][4], bfr[2][4];
#pragma unroll
        for (int kc = 0; kc < 4; kc++) {
            int p = (kc * 2 + kh) ^ fsw;
#pragma unroll
            for (int t = 0; t < 2; t++) {
                af[t][kc]  = *(bf16x8_t*)&As[wm + t * 32 + m32][p * 8];
                bfr[t][kc] = *(bf16x8_t*)&Bs[wn + t * 32 + m32][p * 8];
            }
        }
#pragma unroll
        for (int kc = 0; kc < 4; kc++)
#pragma unroll
            for (int i = 0; i < 2; i++)
#pragma unroll
                for (int j = 0; j < 2; j++)
                    acc[i][j] = __builtin_amdgcn_mfma_f32_32x32x16_bf16(
                        af[i][kc], bfr[j][kc], acc[i][j], 0, 0, 0);
    }

    // epilogue: C/D layout col=lane&31, row=(reg&3)+8*(reg>>2)+4*kh
#pragma unroll
    for (int j = 0; j < 2; j++) {
        int col = colBase + wn + j * 32 + m32;
        float bv = bias[col];
#pragma unroll
        for (int i = 0; i < 2; i++) {
#pragma unroll
            for (int reg = 0; reg < 16; reg++) {
                int row = rowBase + wm + i * 32 + (reg & 3) + 8 * (reg >> 2) + 4 * kh;
                float v = acc[i][j][reg] + bv;
                if (OUT_BF16)
                    ((unsigned short*)C)[(long)row * Ncols + col] = f2bf(v);
                else
                    ((float*)C)[(long)row * Ncols + col] = v;
            }
        }
    }
}

__global__ __launch_bounds__(256)
void gemm_qkv(const unsigned short* __restrict__ A,
              const unsigned short* __restrict__ BT,
              const float* __restrict__ bias,
              void* __restrict__ C, int M, int Ncols, int K) {
    gemm_body<true>(A, BT, bias, C, M, Ncols, K);
}

__global__ __launch_bounds__(256)
void gemm_proj(const unsigned short* __restrict__ A,
               const unsigned short* __restrict__ BT,
               const float* __restrict__ bias,
               void* __restrict__ C, int M, int Ncols, int K) {
    gemm_body<false>(A, BT, bias, C, M, Ncols, K);
}

// ---------------------------------------------------------------------------
// MFMA flash attention v4: v3 tiling, NO forced unroll.
// History: v1 (128 KiB LDS, 1 blk/CU): 193 us, 92 VGPR, Occ 19%.
//          v2 (reg-prefetch): VGPR starvation spill, 1700 us.
//          v3 (64 KiB, #pragma unroll on lt loop): 261 us — unroll inflated
//          live ranges to 128 VGPR + spill (WRITE 64->120 MB is the tell).
// v4 = v3 with `#pragma unroll 1` pinned on kt and lt loops so each
// iteration compiles exactly like v1's non-unrolled ct iteration
// (~92-104 VGPR, no spill) while LDS stays 64 KiB -> true 2 blocks/CU
// (4 waves/SIMD). Math/swizzles bit-identical to v3 (which passed).
__global__ __launch_bounds__(512, 2)
void attn_mfma(const unsigned short* __restrict__ qkv,       // [32768][3072] bf16
               const unsigned long long* __restrict__ adjm,  // [512][8]
               unsigned short* __restrict__ y)               // [32768][1024] bf16
{
    const int h = blockIdx.x;
    const int b = blockIdx.y;
    const int tid  = threadIdx.x;
    const int lane = tid & 63;
    const int w    = tid >> 6;
    const int l16  = lane & 15;
    const int q    = lane >> 4;

    __shared__ __align__(16) unsigned short Ks[256][64];   // 32 KiB
    __shared__ __align__(16) unsigned short Vt[64][256];   // 32 KiB (V^T)

    const long rowB = (long)b * Nz;
    const unsigned short* base = qkv + rowB * NQKV;

    // Q fragments (registers, hoisted — no LDS dependency)
    FragU qf[4][2];
#pragma unroll
    for (int mt = 0; mt < 4; mt++)
#pragma unroll
        for (int kc = 0; kc < 2; kc++)
            qf[mt][kc].h = *(const bf16x8_t*)&base[(long)(w * 64 + mt * 16 + l16) * NQKV
                                                   + h * DHz + kc * 32 + q * 8];

    f32x4_t oacc[4][4];
#pragma unroll
    for (int mt = 0; mt < 4; mt++)
#pragma unroll
        for (int dt = 0; dt < 4; dt++) {
            f32x4_t z = {0.0f, 0.0f, 0.0f, 0.0f};
            oacc[mt][dt] = z;
        }
    float rsum[4] = {0.0f, 0.0f, 0.0f, 0.0f};
    unsigned long long wm[4];

#pragma unroll 1
    for (int kt = 0; kt < 2; kt++) {
        // barrier before overwriting the tile (all reads of previous done)
        if (kt) __syncthreads();

        // ---- stage K tile: 256 rows x 8 chunks, XOR-swizzled ----
        for (int idx = tid; idx < 2048; idx += 512) {
            int n = idx >> 3, cc = idx & 7;
            *(bf16x8_t*)&Ks[n][(cc ^ (n & 7)) * 8] =
                *(const bf16x8_t*)&base[(long)(kt * 256 + n) * NQKV + Ez + h * DHz + cc * 8];
        }
        // ---- stage V^T tile: thread handles rows (n0,n0+1) x 16 d's ----
        {
            int tp = tid & 127, dh = tid >> 7;   // dh in [0,4)
            int n0 = tp * 2;
            bf16x8_t va[2], vb[2];
#pragma unroll
            for (int c = 0; c < 2; c++) {
                va[c] = *(const bf16x8_t*)&base[(long)(kt * 256 + n0) * NQKV + 2 * Ez + h * DHz + dh * 16 + c * 8];
                vb[c] = *(const bf16x8_t*)&base[(long)(kt * 256 + n0 + 1) * NQKV + 2 * Ez + h * DHz + dh * 16 + c * 8];
            }
#pragma unroll
            for (int dd = 0; dd < 16; dd++) {
                int d = dh * 16 + dd;
                unsigned lo = (unsigned)(unsigned short)va[dd >> 3][dd & 7];
                unsigned hi = (unsigned)(unsigned short)vb[dd >> 3][dd & 7];
                int cp = (n0 >> 3) ^ (d & 7);
                *(unsigned*)&Vt[d][cp * 8 + (n0 & 7)] = lo | (hi << 16);
            }
        }
        __syncthreads();

        // ---- 8 column-tiles of 32 within this KV tile (NOT unrolled:
        // full unroll here was v3's 128-VGPR spill) ----
#pragma unroll 1
        for (int lt = 0; lt < 8; lt++) {
            const int ct = kt * 8 + lt;
            if ((ct & 1) == 0) {
#pragma unroll
                for (int mt = 0; mt < 4; mt++)
                    wm[mt] = adjm[(size_t)(w * 64 + mt * 16 + l16) * 8 + (ct >> 1)];
            }
            bf16x8_t kf[2][2];
#pragma unroll
            for (int jt = 0; jt < 2; jt++)
#pragma unroll
                for (int kc = 0; kc < 2; kc++)
                    kf[jt][kc] = *(const bf16x8_t*)
                        &Ks[lt * 32 + jt * 16 + l16][((kc * 4 + q) ^ (l16 & 7)) * 8];

            f32x4_t tacc[2][4];
            __builtin_amdgcn_s_setprio(1);
#pragma unroll
            for (int jt = 0; jt < 2; jt++)
#pragma unroll
                for (int mt = 0; mt < 4; mt++) {
                    f32x4_t z = {0.0f, 0.0f, 0.0f, 0.0f};
                    z = __builtin_amdgcn_mfma_f32_16x16x32_bf16(kf[jt][0], qf[mt][0].h, z, 0, 0, 0);
                    tacc[jt][mt] = __builtin_amdgcn_mfma_f32_16x16x32_bf16(kf[jt][1], qf[mt][1].h, z, 0, 0, 0);
                }
            __builtin_amdgcn_s_setprio(0);

            unsigned pk[2][4][2];
#pragma unroll
            for (int jt = 0; jt < 2; jt++)
#pragma unroll
                for (int mt = 0; mt < 4; mt++) {
                    float e[4];
#pragma unroll
                    for (int r = 0; r < 4; r++) {
                        int jrel = (ct & 1) * 32 + jt * 16 + q * 4 + r;
                        bool bit = (wm[mt] >> jrel) & 1ull;
                        float ev = bit ? __expf(tacc[jt][mt][r] * 0.125f) : 0.0f;
                        e[r] = ev;
                        rsum[mt] += ev;
                    }
                    pk[jt][mt][0] = packbf(e[0], e[1]);
                    pk[jt][mt][1] = packbf(e[2], e[3]);
                }

            bf16x8_t vf[4];
#pragma unroll
            for (int dt = 0; dt < 4; dt++) {
                int d = dt * 16 + l16;
                int cp = (lt * 4 + q) ^ (l16 & 7);
                vf[dt] = *(const bf16x8_t*)&Vt[d][cp * 8];
            }

#pragma unroll
            for (int mt = 0; mt < 4; mt++) {
                FragU pf;
#pragma unroll
                for (int p = 0; p < 4; p++) {
                    int srcl = ((lane & 16) << 1) | ((p & 2) << 3) | l16;
                    unsigned a0 = (unsigned)__shfl((int)pk[0][mt][p & 1], srcl);
                    unsigned a1 = (unsigned)__shfl((int)pk[1][mt][p & 1], srcl);
                    pf.u[p] = (lane & 32) ? a1 : a0;
                }
                __builtin_amdgcn_s_setprio(1);
#pragma unroll
                for (int dt = 0; dt < 4; dt++)
                    oacc[mt][dt] = __builtin_amdgcn_mfma_f32_16x16x32_bf16(
                        pf.h, vf[dt], oacc[mt][dt], 0, 0, 0);
                __builtin_amdgcn_s_setprio(0);
            }
        }
    }

#pragma unroll
    for (int mt = 0; mt < 4; mt++) {
        float s = rsum[mt];
        s += __shfl_xor(s, 16);
        s += __shfl_xor(s, 32);
#pragma unroll
        for (int r = 0; r < 4; r++) {
            float rs = __shfl(s, (lane & 48) | (q * 4) | r);
            float inv = 1.0f / rs;
            int row = w * 64 + mt * 16 + q * 4 + r;
#pragma unroll
            for (int dt = 0; dt < 4; dt++)
                y[(rowB + row) * Ez + h * DHz + dt * 16 + l16] =
                    f2bf(oacc[mt][dt][r] * inv);
        }
    }
}

// ---------------------------------------------------------------------------
extern "C" void kernel_launch(void* const* d_in, const int* in_sizes, int n_in,
                              void* d_out, int out_size, void* d_ws, size_t ws_size,
                              hipStream_t stream) {
    const float* x     = (const float*)d_in[0];
    const float* Wqkv  = (const float*)d_in[1];
    const float* bqkv  = (const float*)d_in[2];
    const float* Wproj = (const float*)d_in[3];
    const float* bproj = (const float*)d_in[4];
    const int*   adj   = (const int*)d_in[5];
    float* out = (float*)d_out;

    char* ws = (char*)d_ws;
    unsigned short* xb     = (unsigned short*)(ws);                 // 67 MB (also yb)
    unsigned short* qkv    = (unsigned short*)(ws + 67108864);      // 201 MB
    unsigned short* WqkvT  = (unsigned short*)(ws + 268435456);     // 6 MB
    unsigned short* WprojT = (unsigned short*)(ws + 274726912);     // 2 MB
    unsigned long long* adjm = (unsigned long long*)(ws + 276824064); // 32 KB
    unsigned short* yb = xb;  // reuse: xb consumed by gemm1 before attn writes yb

    // 1. casts / transposes / adjacency bitmask
    cvt_f32_bf16<<<8192, 256, 0, stream>>>(x, xb, (Bz * Nz * Ez) / 4);
    cvt_transpose<<<dim3(NQKV / 256, Ez / 8), 256, 0, stream>>>(Wqkv, WqkvT, Ez, NQKV);
    cvt_transpose<<<dim3(Ez / 256, Ez / 8), 256, 0, stream>>>(Wproj, WprojT, Ez, Ez);
    build_adjm<<<16, 256, 0, stream>>>(adj, adjm);

    // 2. QKV projection (fused single launch)
    gemm_qkv<<<dim3(NQKV / 128, MROWS / 128), 256, 0, stream>>>(
        xb, WqkvT, bqkv, qkv, MROWS, NQKV, Ez);

    // 3. MFMA flash attention (2x256 KV tiles, 64 KiB LDS -> 2 blocks/CU)
    attn_mfma<<<dim3(Hz, Bz), 512, 0, stream>>>(qkv, adjm, yb);

    // 4. output projection: out = yb @ Wproj + bproj (fp32 out)
    gemm_proj<<<dim3(Ez / 128, MROWS / 128), 256, 0, stream>>>(
        yb, WprojT, bproj, out, MROWS, Ez, Ez);
}

// Round 14
// 740.218 us; speedup vs baseline: 3.0340x; 1.0364x over previous
//
#include <hip/hip_runtime.h>
#include <hip/hip_bf16.h>

// Problem constants
#define Bz 64
#define Nz 512
#define Ez 1024
#define Hz 16
#define DHz 64

static constexpr int MROWS = Bz * Nz;   // 32768
static constexpr int NQKV  = 3 * Ez;    // 3072

typedef __attribute__((ext_vector_type(8))) short bf16x8_t;   // 8 bf16 = 4 VGPRs
typedef __attribute__((ext_vector_type(4))) float f32x4_t;
typedef __attribute__((ext_vector_type(16))) float f32x16_t;
typedef __attribute__((ext_vector_type(4))) unsigned u32x4_t;

union FragU { bf16x8_t h; u32x4_t u; };

__device__ __forceinline__ unsigned short f2bf(float f) {
    union { float f; unsigned u; } v; v.f = f;
    unsigned r = v.u + 0x7FFFu + ((v.u >> 16) & 1u);   // round-to-nearest-even
    return (unsigned short)(r >> 16);
}
__device__ __forceinline__ float bf2f(unsigned short h) {
    union { unsigned u; float f; } v; v.u = ((unsigned)h) << 16;
    return v.f;
}
// pack two non-negative floats to bf16 pair (lo | hi<<16), round-half-up
__device__ __forceinline__ unsigned packbf(float a, float b) {
    union { float f; unsigned u; } x, y; x.f = a; y.f = b;
    return ((x.u + 0x8000u) >> 16) | ((y.u + 0x8000u) & 0xFFFF0000u);
}

// async global->LDS, 16B per lane. LDS dest = wave-uniform base + lane*16.
__device__ __forceinline__ void async16(const unsigned short* g, unsigned short* l) {
    __builtin_amdgcn_global_load_lds(
        (const __attribute__((address_space(1))) void*)g,
        (__attribute__((address_space(3))) void*)l, 16, 0, 0);
}

// ---------------------------------------------------------------------------
// Fused prologue: one dispatch replaces {cvt_f32_bf16, cvt_transpose x2,
// build_adjm} (all mutually independent; bodies byte-identical to the
// measured standalone kernels). Removes 3 launch gaps. Block-uniform branch.
//   blocks [0, 8192):          x f32 -> xb bf16 (grid-stride float4)
//   blocks [8192, 9728):       Wqkv [Ez][NQKV] -> WqkvT [NQKV][Ez] bf16
//   blocks [9728, 10240):      Wproj [Ez][Ez]  -> WprojT [Ez][Ez]  bf16
//   blocks [10240, 10256):     adj -> adjm bitmask (self-loops baked in)
__global__ __launch_bounds__(256)
void prep_all(const float* __restrict__ x, unsigned short* __restrict__ xb,
              const float* __restrict__ Wqkv, unsigned short* __restrict__ WqkvT,
              const float* __restrict__ Wproj, unsigned short* __restrict__ WprojT,
              const int* __restrict__ adj, unsigned long long* __restrict__ adjm) {
    const int bid = blockIdx.x;
    const int tid = threadIdx.x;
    if (bid < 8192) {
        const int n4 = (Bz * Nz * Ez) / 4;          // 8,388,608
        int id = bid * 256 + tid;
        const int stride = 8192 * 256;              // 4 iters/thread
        for (int i = id; i < n4; i += stride) {
            float4 f = ((const float4*)x)[i];
            ushort4 o;
            o.x = f2bf(f.x); o.y = f2bf(f.y); o.z = f2bf(f.z); o.w = f2bf(f.w);
            ((ushort4*)xb)[i] = o;
        }
    } else if (bid < 8192 + 1536) {
        // Wqkv transpose: K=Ez rows, Ncols=NQKV. 12 n-blocks x 128 k-blocks.
        int r  = bid - 8192;
        int n  = (r % 12) * 256 + tid;
        int k0 = (r / 12) * 8;
        bf16x8_t o;
#pragma unroll
        for (int j = 0; j < 8; j++)
            o[j] = (short)f2bf(Wqkv[(long)(k0 + j) * NQKV + n]);
        *(bf16x8_t*)&WqkvT[(long)n * Ez + k0] = o;
    } else if (bid < 8192 + 1536 + 512) {
        // Wproj transpose: K=Ez, Ncols=Ez. 4 n-blocks x 128 k-blocks.
        int r  = bid - (8192 + 1536);
        int n  = (r % 4) * 256 + tid;
        int k0 = (r / 4) * 8;
        bf16x8_t o;
#pragma unroll
        for (int j = 0; j < 8; j++)
            o[j] = (short)f2bf(Wproj[(long)(k0 + j) * Ez + n]);
        *(bf16x8_t*)&WprojT[(long)n * Ez + k0] = o;
    } else {
        int id = (bid - (8192 + 1536 + 512)) * 256 + tid;   // 0..4095
        int n = id >> 3, w = id & 7;
        const int4* r4 = (const int4*)(adj + (long)n * Nz + w * 64);
        unsigned long long m = 0;
#pragma unroll
        for (int c = 0; c < 16; c++) {
            int4 v = r4[c];
            unsigned long long bits =
                (unsigned long long)(v.x != 0) | ((unsigned long long)(v.y != 0) << 1) |
                ((unsigned long long)(v.z != 0) << 2) | ((unsigned long long)(v.w != 0) << 3);
            m |= bits << (c * 4);
        }
        if ((n >> 6) == w) m |= 1ull << (n & 63);
        adjm[id] = m;
    }
}

// ---------------------------------------------------------------------------
// bf16 MFMA GEMM v4 (measured best: ~838 TF): C = A @ BT^T + bias.
// 128x128 block tile, BK=64, 256 threads (4 waves), 32x32x16 MFMA,
// global_load_lds width-16 staging, XOR-8 chunk swizzle (p = c ^ (row&7)).
// 32 KiB LDS -> ~3 blocks/CU; implicit wave-level overlap (m114). FROZEN:
// both 256²-tile deep-pipeline ports (r1/r2) lost to this structure.
template<bool OUT_BF16>
__device__ __forceinline__
void gemm_body(const unsigned short* __restrict__ A,
               const unsigned short* __restrict__ BT,
               const float* __restrict__ bias,
               void* __restrict__ C,
               int M, int Ncols, int K) {
    const int tid  = threadIdx.x;
    const int wave = tid >> 6;
    const int lane = tid & 63;
    const int wm = (wave >> 1) * 64;
    const int wn = (wave & 1) * 64;
    const int m32 = lane & 31;     // row within 32-tile
    const int kh  = lane >> 5;     // k-half selector

    const int rowBase = blockIdx.y * 128;
    const int colBase = blockIdx.x * 128;

    __shared__ __align__(16) unsigned short As[128][64];   // 16 KiB
    __shared__ __align__(16) unsigned short Bs[128][64];   // 16 KiB

    f32x16_t acc[2][2];
#pragma unroll
    for (int i = 0; i < 2; i++)
#pragma unroll
        for (int j = 0; j < 2; j++)
#pragma unroll
            for (int r = 0; r < 16; r++)
                acc[i][j][r] = 0.0f;

    // staging: slot s = tid + cc*256 (s in [0,1024)); row = s>>3, physical
    // chunk p = s&7 holds logical chunk c = p ^ (row&7). Global addresses of
    // 8 consecutive lanes permute within one 128B row segment -> coalesced.
    const unsigned short* pa[4];
    const unsigned short* pb[4];
#pragma unroll
    for (int cc = 0; cc < 4; cc++) {
        int s = tid + cc * 256;
        int r = s >> 3;
        int c = (s & 7) ^ (r & 7);
        pa[cc] = &A [(long)(rowBase + r) * K + c * 8];
        pb[cc] = &BT[(long)(colBase + r) * K + c * 8];
    }
    // fragment-read physical chunk, per kc: p = (kc*2 + kh) ^ (m32&7)
    const int fsw = m32 & 7;

    for (int k0 = 0; k0 < K; k0 += 64) {
        __syncthreads();
#pragma unroll
        for (int cc = 0; cc < 4; cc++) {
            async16(pa[cc] + k0, (unsigned short*)As + (size_t)(cc * 64 + wave * 16) * 32);
            async16(pb[cc] + k0, (unsigned short*)Bs + (size_t)(cc * 64 + wave * 16) * 32);
        }
        __syncthreads();

        bf16x8_t af[2][4], bfr[2][4];
#pragma unroll
        for (int kc = 0; kc < 4; kc++) {
            int p = (kc * 2 + kh) ^ fsw;
#pragma unroll
            for (int t = 0; t < 2; t++) {
                af[t][kc]  = *(bf16x8_t*)&As[wm + t * 32 + m32][p * 8];
                bfr[t][kc] = *(bf16x8_t*)&Bs[wn + t * 32 + m32][p * 8];
            }
        }
#pragma unroll
        for (int kc = 0; kc < 4; kc++)
#pragma unroll
            for (int i = 0; i < 2; i++)
#pragma unroll
                for (int j = 0; j < 2; j++)
                    acc[i][j] = __builtin_amdgcn_mfma_f32_32x32x16_bf16(
                        af[i][kc], bfr[j][kc], acc[i][j], 0, 0, 0);
    }

    // epilogue: C/D layout col=lane&31, row=(reg&3)+8*(reg>>2)+4*kh
#pragma unroll
    for (int j = 0; j < 2; j++) {
        int col = colBase + wn + j * 32 + m32;
        float bv = bias[col];
#pragma unroll
        for (int i = 0; i < 2; i++) {
#pragma unroll
            for (int reg = 0; reg < 16; reg++) {
                int row = rowBase + wm + i * 32 + (reg & 3) + 8 * (reg >> 2) + 4 * kh;
                float v = acc[i][j][reg] + bv;
                if (OUT_BF16)
                    ((unsigned short*)C)[(long)row * Ncols + col] = f2bf(v);
                else
                    ((float*)C)[(long)row * Ncols + col] = v;
            }
        }
    }
}

__global__ __launch_bounds__(256)
void gemm_qkv(const unsigned short* __restrict__ A,
              const unsigned short* __restrict__ BT,
              const float* __restrict__ bias,
              void* __restrict__ C, int M, int Ncols, int K) {
    gemm_body<true>(A, BT, bias, C, M, Ncols, K);
}

__global__ __launch_bounds__(256)
void gemm_proj(const unsigned short* __restrict__ A,
               const unsigned short* __restrict__ BT,
               const float* __restrict__ bias,
               void* __restrict__ C, int M, int Ncols, int K) {
    gemm_body<false>(A, BT, bias, C, M, Ncols, K);
}

// ---------------------------------------------------------------------------
// MFMA flash attention v1 (measured 193 us; FROZEN — v2 spilled 1700us,
// v3 unroll-spilled 261us, v4 clean-reg 2blk/CU ~214us: the single-staging
// 16-ct barrier-free loop beats every KV-tiled variant). One block per
// (b,h); 8 waves, wave w owns Q rows [w*64, w*64+64). S^T = K @ Q^T via
// 16x16x32 MFMA, exp+mask in C-layout, shuffle re-layout P -> A-operand,
// PV MFMA with V staged transposed. s_setprio(1) around MFMA clusters.
__global__ __launch_bounds__(512, 2)
void attn_mfma(const unsigned short* __restrict__ qkv,       // [32768][3072] bf16
               const unsigned long long* __restrict__ adjm,  // [512][8]
               unsigned short* __restrict__ y)               // [32768][1024] bf16
{
    const int h = blockIdx.x;
    const int b = blockIdx.y;
    const int tid  = threadIdx.x;
    const int lane = tid & 63;
    const int w    = tid >> 6;
    const int l16  = lane & 15;
    const int q    = lane >> 4;

    __shared__ __align__(16) unsigned short Ks[512][64];   // 64 KiB
    __shared__ __align__(16) unsigned short Vt[64][512];   // 64 KiB (V^T)

    const long rowB = (long)b * Nz;
    const unsigned short* base = qkv + rowB * NQKV;

    for (int idx = tid; idx < 4096; idx += 512) {
        int n = idx >> 3, cc = idx & 7;
        *(bf16x8_t*)&Ks[n][(cc ^ (n & 7)) * 8] =
            *(const bf16x8_t*)&base[(long)n * NQKV + Ez + h * DHz + cc * 8];
    }
    {
        int tp = tid & 255, dh = tid >> 8;
        int n0 = tp * 2;
        bf16x8_t va[4], vb[4];
#pragma unroll
        for (int c = 0; c < 4; c++) {
            va[c] = *(const bf16x8_t*)&base[(long)n0 * NQKV + 2 * Ez + h * DHz + dh * 32 + c * 8];
            vb[c] = *(const bf16x8_t*)&base[(long)(n0 + 1) * NQKV + 2 * Ez + h * DHz + dh * 32 + c * 8];
        }
        unsigned short* vt = &Vt[0][0];
#pragma unroll
        for (int dd = 0; dd < 32; dd++) {
            int d = dh * 32 + dd;
            unsigned lo = (unsigned)(unsigned short)va[dd >> 3][dd & 7];
            unsigned hi = (unsigned)(unsigned short)vb[dd >> 3][dd & 7];
            int cp = (n0 >> 3) ^ (d & 7);
            *(unsigned*)&vt[d * 512 + cp * 8 + (n0 & 7)] = lo | (hi << 16);
        }
    }
    FragU qf[4][2];
#pragma unroll
    for (int mt = 0; mt < 4; mt++)
#pragma unroll
        for (int kc = 0; kc < 2; kc++)
            qf[mt][kc].h = *(const bf16x8_t*)&base[(long)(w * 64 + mt * 16 + l16) * NQKV
                                                   + h * DHz + kc * 32 + q * 8];
    __syncthreads();

    f32x4_t oacc[4][4];
#pragma unroll
    for (int mt = 0; mt < 4; mt++)
#pragma unroll
        for (int dt = 0; dt < 4; dt++) {
            f32x4_t z = {0.0f, 0.0f, 0.0f, 0.0f};
            oacc[mt][dt] = z;
        }
    float rsum[4] = {0.0f, 0.0f, 0.0f, 0.0f};
    unsigned long long wm[4];

    for (int ct = 0; ct < 16; ct++) {
        const int j0 = ct * 32;
        if ((ct & 1) == 0) {
#pragma unroll
            for (int mt = 0; mt < 4; mt++)
                wm[mt] = adjm[(size_t)(w * 64 + mt * 16 + l16) * 8 + (ct >> 1)];
        }
        bf16x8_t kf[2][2];
#pragma unroll
        for (int jt = 0; jt < 2; jt++)
#pragma unroll
            for (int kc = 0; kc < 2; kc++)
                kf[jt][kc] = *(const bf16x8_t*)
                    &Ks[j0 + jt * 16 + l16][((kc * 4 + q) ^ (l16 & 7)) * 8];

        f32x4_t tacc[2][4];
        __builtin_amdgcn_s_setprio(1);
#pragma unroll
        for (int jt = 0; jt < 2; jt++)
#pragma unroll
            for (int mt = 0; mt < 4; mt++) {
                f32x4_t z = {0.0f, 0.0f, 0.0f, 0.0f};
                z = __builtin_amdgcn_mfma_f32_16x16x32_bf16(kf[jt][0], qf[mt][0].h, z, 0, 0, 0);
                tacc[jt][mt] = __builtin_amdgcn_mfma_f32_16x16x32_bf16(kf[jt][1], qf[mt][1].h, z, 0, 0, 0);
            }
        __builtin_amdgcn_s_setprio(0);

        unsigned pk[2][4][2];
#pragma unroll
        for (int jt = 0; jt < 2; jt++)
#pragma unroll
            for (int mt = 0; mt < 4; mt++) {
                float e[4];
#pragma unroll
                for (int r = 0; r < 4; r++) {
                    int jrel = (ct & 1) * 32 + jt * 16 + q * 4 + r;
                    bool bit = (wm[mt] >> jrel) & 1ull;
                    float ev = bit ? __expf(tacc[jt][mt][r] * 0.125f) : 0.0f;
                    e[r] = ev;
                    rsum[mt] += ev;
                }
                pk[jt][mt][0] = packbf(e[0], e[1]);
                pk[jt][mt][1] = packbf(e[2], e[3]);
            }

        bf16x8_t vf[4];
#pragma unroll
        for (int dt = 0; dt < 4; dt++) {
            int d = dt * 16 + l16;
            int cp = (ct * 4 + q) ^ (l16 & 7);
            vf[dt] = *(const bf16x8_t*)&(&Vt[0][0])[d * 512 + cp * 8];
        }

#pragma unroll
        for (int mt = 0; mt < 4; mt++) {
            FragU pf;
#pragma unroll
            for (int p = 0; p < 4; p++) {
                int srcl = ((lane & 16) << 1) | ((p & 2) << 3) | l16;
                unsigned a0 = (unsigned)__shfl((int)pk[0][mt][p & 1], srcl);
                unsigned a1 = (unsigned)__shfl((int)pk[1][mt][p & 1], srcl);
                pf.u[p] = (lane & 32) ? a1 : a0;
            }
            __builtin_amdgcn_s_setprio(1);
#pragma unroll
            for (int dt = 0; dt < 4; dt++)
                oacc[mt][dt] = __builtin_amdgcn_mfma_f32_16x16x32_bf16(
                    pf.h, vf[dt], oacc[mt][dt], 0, 0, 0);
            __builtin_amdgcn_s_setprio(0);
        }
    }

#pragma unroll
    for (int mt = 0; mt < 4; mt++) {
        float s = rsum[mt];
        s += __shfl_xor(s, 16);
        s += __shfl_xor(s, 32);
#pragma unroll
        for (int r = 0; r < 4; r++) {
            float rs = __shfl(s, (lane & 48) | (q * 4) | r);
            float inv = 1.0f / rs;
            int row = w * 64 + mt * 16 + q * 4 + r;
#pragma unroll
            for (int dt = 0; dt < 4; dt++)
                y[(rowB + row) * Ez + h * DHz + dt * 16 + l16] =
                    f2bf(oacc[mt][dt][r] * inv);
        }
    }
}

// ---------------------------------------------------------------------------
extern "C" void kernel_launch(void* const* d_in, const int* in_sizes, int n_in,
                              void* d_out, int out_size, void* d_ws, size_t ws_size,
                              hipStream_t stream) {
    const float* x     = (const float*)d_in[0];
    const float* Wqkv  = (const float*)d_in[1];
    const float* bqkv  = (const float*)d_in[2];
    const float* Wproj = (const float*)d_in[3];
    const float* bproj = (const float*)d_in[4];
    const int*   adj   = (const int*)d_in[5];
    float* out = (float*)d_out;

    char* ws = (char*)d_ws;
    unsigned short* xb     = (unsigned short*)(ws);                 // 67 MB (also yb)
    unsigned short* qkv    = (unsigned short*)(ws + 67108864);      // 201 MB
    unsigned short* WqkvT  = (unsigned short*)(ws + 268435456);     // 6 MB
    unsigned short* WprojT = (unsigned short*)(ws + 274726912);     // 2 MB
    unsigned long long* adjm = (unsigned long long*)(ws + 276824064); // 32 KB
    unsigned short* yb = xb;  // reuse: xb consumed by gemm1 before attn writes yb

    // 1. fused prologue: casts + transposes + adjacency bitmask (1 dispatch)
    prep_all<<<8192 + 1536 + 512 + 16, 256, 0, stream>>>(
        x, xb, Wqkv, WqkvT, Wproj, WprojT, adj, adjm);

    // 2. QKV projection: qkv = xb @ Wqkv + bqkv (bf16 out)
    gemm_qkv<<<dim3(NQKV / 128, MROWS / 128), 256, 0, stream>>>(
        xb, WqkvT, bqkv, qkv, MROWS, NQKV, Ez);

    // 3. MFMA flash attention (v1, frozen)
    attn_mfma<<<dim3(Hz, Bz), 512, 0, stream>>>(qkv, adjm, yb);

    // 4. output projection: out = yb @ Wproj + bproj (fp32 out)
    gemm_proj<<<dim3(Ez / 128, MROWS / 128), 256, 0, stream>>>(
        yb, WprojT, bproj, out, MROWS, Ez, Ez);
}